// Round 1
// baseline (10649.802 us; speedup 1.0000x reference)
//
#include <hip/hip_runtime.h>
#include <stdint.h>
#include <stddef.h>

#define B_ 128
#define T_ 256
#define I_ 256
#define H_ 1024
#define O_ 128

typedef __attribute__((ext_vector_type(8))) __bf16 bf16x8;
typedef __attribute__((ext_vector_type(4))) float f32x4;

// ---------------------------------------------------------------- utilities

// split fp32 -> bf16 (hi) + bf16 residual (lo); hi+lo ~ fp32 to ~2^-17 rel
__global__ void split_kernel(const float* __restrict__ src, __bf16* __restrict__ hi,
                             __bf16* __restrict__ lo, int n) {
    int i = blockIdx.x * blockDim.x + threadIdx.x;
    int stride = gridDim.x * blockDim.x;
    for (; i < n; i += stride) {
        float v = src[i];
        __bf16 h = (__bf16)v;               // RNE
        hi[i] = h;
        lo[i] = (__bf16)(v - (float)h);
    }
}

// W_fc (O,H) -> Wt (H,O) fp32, so FC reads are lane-coalesced over o
__global__ void transpose_fc(const float* __restrict__ w, float* __restrict__ wt) {
    int i = blockIdx.x * blockDim.x + threadIdx.x;
    if (i < O_ * H_) {
        int o = i / H_, k = i - o * H_;
        wt[k * O_ + o] = w[i];
    }
}

// ---------------------------------------------------------------- RNN step
//
// One launch = one time step of one layer:
//   h_out[b][j] = tanh( sum_k A0[b][k]*W0[j][k]        (input segment, K0)
//               +       sum_k S[b][k]*W1[j][k]         (recurrent, K=H)
//               +       bias0[j] + bias1[j] )
// 3-term bf16 hi/lo MFMA accumulation in fp32.
// Grid: 512 blocks x 64 threads; block = one wave = one 16x16 C tile.
// C tile (bt,jt): rows b = bt*16.., cols j = jt*16..
__global__ __launch_bounds__(64) void step_kernel(
    const __bf16* __restrict__ A0h, const __bf16* __restrict__ A0l, long lda0, int K0,
    const __bf16* __restrict__ W0h, const __bf16* __restrict__ W0l,
    const __bf16* __restrict__ Sh,  const __bf16* __restrict__ Sl,   // state in (B,H)
    const __bf16* __restrict__ W1h, const __bf16* __restrict__ W1l,
    const float* __restrict__ bias0, const float* __restrict__ bias1,
    __bf16* __restrict__ Oh, __bf16* __restrict__ Ol,                // state out (B,H)
    __bf16* __restrict__ Sqh, __bf16* __restrict__ Sql, long ldsq,   // optional per-t output
    float* __restrict__ Of32)                                        // optional fp32 out (B,H)
{
    const int tile = blockIdx.x;       // 0..511
    const int jt = tile & 63;          // 64 col tiles
    const int bt = tile >> 6;          // 8 row tiles
    const int lane = threadIdx.x;      // 0..63
    const int ln = lane & 15;
    const int q  = lane >> 4;

    f32x4 acc = {0.f, 0.f, 0.f, 0.f};

    const int arow = bt * 16 + ln;     // A fragment row: m = lane&15
    const int brow = jt * 16 + ln;     // B fragment row (W row j): n = lane&15

    // ---- segment 0: input contribution (K0 = 256 for layer0, 1024 for layer1)
    {
        const __bf16* ah_p = A0h + (long)arow * lda0 + q * 8;
        const __bf16* al_p = A0l + (long)arow * lda0 + q * 8;
        const __bf16* bh_p = W0h + (long)brow * K0 + q * 8;
        const __bf16* bl_p = W0l + (long)brow * K0 + q * 8;
        #pragma unroll 2
        for (int kk = 0; kk < K0; kk += 32) {
            bf16x8 ah = *(const bf16x8*)(ah_p + kk);
            bf16x8 al = *(const bf16x8*)(al_p + kk);
            bf16x8 bh = *(const bf16x8*)(bh_p + kk);
            bf16x8 bl = *(const bf16x8*)(bl_p + kk);
            acc = __builtin_amdgcn_mfma_f32_16x16x32_bf16(ah, bh, acc, 0, 0, 0);
            acc = __builtin_amdgcn_mfma_f32_16x16x32_bf16(al, bh, acc, 0, 0, 0);
            acc = __builtin_amdgcn_mfma_f32_16x16x32_bf16(ah, bl, acc, 0, 0, 0);
        }
    }
    // ---- segment 1: recurrent contribution (K = H)
    {
        const __bf16* ah_p = Sh + (long)arow * H_ + q * 8;
        const __bf16* al_p = Sl + (long)arow * H_ + q * 8;
        const __bf16* bh_p = W1h + (long)brow * H_ + q * 8;
        const __bf16* bl_p = W1l + (long)brow * H_ + q * 8;
        #pragma unroll 2
        for (int kk = 0; kk < H_; kk += 32) {
            bf16x8 ah = *(const bf16x8*)(ah_p + kk);
            bf16x8 al = *(const bf16x8*)(al_p + kk);
            bf16x8 bh = *(const bf16x8*)(bh_p + kk);
            bf16x8 bl = *(const bf16x8*)(bl_p + kk);
            acc = __builtin_amdgcn_mfma_f32_16x16x32_bf16(ah, bh, acc, 0, 0, 0);
            acc = __builtin_amdgcn_mfma_f32_16x16x32_bf16(al, bh, acc, 0, 0, 0);
            acc = __builtin_amdgcn_mfma_f32_16x16x32_bf16(ah, bl, acc, 0, 0, 0);
        }
    }

    // ---- epilogue: C/D layout col=lane&15, row=(lane>>4)*4+reg  [m89/m91]
    const int j = jt * 16 + ln;
    const float bj = bias0[j] + bias1[j];
    #pragma unroll
    for (int r = 0; r < 4; ++r) {
        int b = bt * 16 + q * 4 + r;
        float h = tanhf(acc[r] + bj);
        __bf16 hh = (__bf16)h;
        __bf16 hl = (__bf16)(h - (float)hh);
        Oh[(long)b * H_ + j] = hh;
        Ol[(long)b * H_ + j] = hl;
        if (Sqh) { Sqh[(long)b * ldsq + j] = hh; Sql[(long)b * ldsq + j] = hl; }
        if (Of32) { Of32[(long)b * H_ + j] = h; }
    }
}

// ---------------------------------------------------------------- final FC
__global__ __launch_bounds__(128) void fc_kernel(const float* __restrict__ h2,
                                                 const float* __restrict__ wt,
                                                 const float* __restrict__ bfc,
                                                 float* __restrict__ out) {
    int b = blockIdx.x;    // 128
    int o = threadIdx.x;   // 128
    const float* hrow = h2 + (long)b * H_;
    float acc = 0.f;
    #pragma unroll 4
    for (int k = 0; k < H_; ++k)
        acc += hrow[k] * wt[k * O_ + o];
    out[b * O_ + o] = acc + bfc[o];
}

// ---------------------------------------------------------------- launch

extern "C" void kernel_launch(void* const* d_in, const int* in_sizes, int n_in,
                              void* d_out, int out_size, void* d_ws, size_t ws_size,
                              hipStream_t stream) {
    const float* X     = (const float*)d_in[0];
    const float* Wih0  = (const float*)d_in[1];
    const float* Whh0  = (const float*)d_in[2];
    const float* bih0  = (const float*)d_in[3];
    const float* bhh0  = (const float*)d_in[4];
    const float* Wih1  = (const float*)d_in[5];
    const float* Whh1  = (const float*)d_in[6];
    const float* bih1  = (const float*)d_in[7];
    const float* bhh1  = (const float*)d_in[8];
    const float* Wfc   = (const float*)d_in[9];
    const float* bfc   = (const float*)d_in[10];
    float* out = (float*)d_out;

    // ---- workspace carve (256B aligned chunks)
    char* p = (char*)d_ws;
    auto alloc = [&](size_t bytes) -> void* {
        void* r = (void*)p;
        p += (bytes + 255) & ~(size_t)255;
        return r;
    };
    const size_t nX = (size_t)B_ * T_ * I_;       // 8388608
    const size_t nW0 = (size_t)H_ * I_;           // 262144
    const size_t nW = (size_t)H_ * H_;            // 1048576
    const size_t nH1 = (size_t)B_ * T_ * H_;      // 33554432
    __bf16* Xh  = (__bf16*)alloc(nX * 2);
    __bf16* Xl  = (__bf16*)alloc(nX * 2);
    __bf16* W0h = (__bf16*)alloc(nW0 * 2);
    __bf16* W0l = (__bf16*)alloc(nW0 * 2);
    __bf16* Wh0h = (__bf16*)alloc(nW * 2);
    __bf16* Wh0l = (__bf16*)alloc(nW * 2);
    __bf16* Wi1h = (__bf16*)alloc(nW * 2);
    __bf16* Wi1l = (__bf16*)alloc(nW * 2);
    __bf16* Wh1h = (__bf16*)alloc(nW * 2);
    __bf16* Wh1l = (__bf16*)alloc(nW * 2);
    __bf16* h1h = (__bf16*)alloc(nH1 * 2);
    __bf16* h1l = (__bf16*)alloc(nH1 * 2);
    __bf16* s0h = (__bf16*)alloc((size_t)B_ * H_ * 2);
    __bf16* s0l = (__bf16*)alloc((size_t)B_ * H_ * 2);
    __bf16* s1h = (__bf16*)alloc((size_t)B_ * H_ * 2);
    __bf16* s1l = (__bf16*)alloc((size_t)B_ * H_ * 2);
    float* h2f  = (float*)alloc((size_t)B_ * H_ * 4);
    float* wfct = (float*)alloc((size_t)H_ * O_ * 4);
    (void)ws_size; (void)n_in; (void)in_sizes; (void)out_size;

    // ---- precompute: hi/lo splits + W_fc transpose
    split_kernel<<<2048, 256, 0, stream>>>(X, Xh, Xl, (int)nX);
    split_kernel<<<512, 256, 0, stream>>>(Wih0, W0h, W0l, (int)nW0);
    split_kernel<<<1024, 256, 0, stream>>>(Whh0, Wh0h, Wh0l, (int)nW);
    split_kernel<<<1024, 256, 0, stream>>>(Wih1, Wi1h, Wi1l, (int)nW);
    split_kernel<<<1024, 256, 0, stream>>>(Whh1, Wh1h, Wh1l, (int)nW);
    transpose_fc<<<(O_ * H_ + 255) / 256, 256, 0, stream>>>(Wfc, wfct);

    // ---- layer 0: h1[b,t,:] = tanh(X_t@Wih0^T + h@Whh0^T + b)
    hipMemsetAsync(s0h, 0, (size_t)B_ * H_ * 2, stream);
    hipMemsetAsync(s0l, 0, (size_t)B_ * H_ * 2, stream);
    for (int t = 0; t < T_; ++t) {
        const __bf16* sih = (t & 1) ? s1h : s0h;
        const __bf16* sil = (t & 1) ? s1l : s0l;
        __bf16* soh = (t & 1) ? s0h : s1h;
        __bf16* sol = (t & 1) ? s0l : s1l;
        step_kernel<<<512, 64, 0, stream>>>(
            Xh + (long)t * I_, Xl + (long)t * I_, (long)T_ * I_, I_,
            W0h, W0l, sih, sil, Wh0h, Wh0l, bih0, bhh0,
            soh, sol, h1h + (long)t * H_, h1l + (long)t * H_, (long)T_ * H_,
            (float*)nullptr);
    }

    // ---- layer 1: h2 = tanh(h1_t@Wih1^T + h@Whh1^T + b); only final h needed
    hipMemsetAsync(s0h, 0, (size_t)B_ * H_ * 2, stream);
    hipMemsetAsync(s0l, 0, (size_t)B_ * H_ * 2, stream);
    for (int t = 0; t < T_; ++t) {
        const __bf16* sih = (t & 1) ? s1h : s0h;
        const __bf16* sil = (t & 1) ? s1l : s0l;
        __bf16* soh = (t & 1) ? s0h : s1h;
        __bf16* sol = (t & 1) ? s0l : s1l;
        step_kernel<<<512, 64, 0, stream>>>(
            h1h + (long)t * H_, h1l + (long)t * H_, (long)T_ * H_, H_,
            Wi1h, Wi1l, sih, sil, Wh1h, Wh1l, bih1, bhh1,
            soh, sol, (__bf16*)nullptr, (__bf16*)nullptr, 0,
            (t == T_ - 1) ? h2f : (float*)nullptr);
    }

    // ---- FC: out = h2_last @ Wfc^T + bfc
    fc_kernel<<<B_, O_, 0, stream>>>(h2f, wfct, bfc, out);
}

// Round 2
// 5458.141 us; speedup vs baseline: 1.9512x; 1.9512x over previous
//
#include <hip/hip_runtime.h>
#include <stdint.h>
#include <stddef.h>

#define B_ 128
#define T_ 256
#define I_ 256
#define H_ 1024
#define O_ 128

typedef __attribute__((ext_vector_type(8))) __bf16 bf16x8;
typedef __attribute__((ext_vector_type(4))) float f32x4;

// ---------------------------------------------------------------- utilities

// split fp32 -> bf16 (hi) + bf16 residual (lo); hi+lo ~ fp32 to ~2^-17 rel
__global__ void split_kernel(const float* __restrict__ src, __bf16* __restrict__ hi,
                             __bf16* __restrict__ lo, int n) {
    int i = blockIdx.x * blockDim.x + threadIdx.x;
    int stride = gridDim.x * blockDim.x;
    for (; i < n; i += stride) {
        float v = src[i];
        __bf16 h = (__bf16)v;               // RNE
        hi[i] = h;
        lo[i] = (__bf16)(v - (float)h);
    }
}

__global__ void bias_sum_kernel(const float* __restrict__ a, const float* __restrict__ b,
                                float* __restrict__ o, int n) {
    int i = blockIdx.x * blockDim.x + threadIdx.x;
    if (i < n) o[i] = a[i] + b[i];
}

// W_fc (O,H) -> Wt (H,O) fp32, so FC reads are lane-coalesced over o
__global__ void transpose_fc(const float* __restrict__ w, float* __restrict__ wt) {
    int i = blockIdx.x * blockDim.x + threadIdx.x;
    if (i < O_ * H_) {
        int o = i / H_, k = i - o * H_;
        wt[k * O_ + o] = w[i];
    }
}

__device__ __forceinline__ void mfma3(f32x4* acc, bf16x8 ah, bf16x8 al,
                                      bf16x8 bh, bf16x8 bl) {
    acc[0] = __builtin_amdgcn_mfma_f32_16x16x32_bf16(ah, bh, acc[0], 0, 0, 0);
    acc[1] = __builtin_amdgcn_mfma_f32_16x16x32_bf16(al, bh, acc[1], 0, 0, 0);
    acc[2] = __builtin_amdgcn_mfma_f32_16x16x32_bf16(ah, bl, acc[2], 0, 0, 0);
}

// ---------------------------------------------------------------- fused step
//
// One launch = layer0 step t (blocks 0..255) + layer1 step t-1 (blocks 256..511).
// Per layer: 8 bt x 32 jt tiles of 16x32; block = 4 waves, 4-way K-split with
// LDS reduction. 3-term bf16 hi/lo MFMA, fp32 accumulate, tanh epilogue,
// re-split state to hi/lo.
__global__ __launch_bounds__(256) void fused_step(
    int act0, const __bf16* __restrict__ A0h, const __bf16* __restrict__ A0l,
    long lda0_, int K00,
    const __bf16* __restrict__ Wi0h, const __bf16* __restrict__ Wi0l,
    const __bf16* __restrict__ Wr0h, const __bf16* __restrict__ Wr0l,
    const float* __restrict__ bs0,
    const __bf16* __restrict__ S0h, const __bf16* __restrict__ S0l,
    __bf16* __restrict__ O0h, __bf16* __restrict__ O0l,
    __bf16* __restrict__ Q0h, __bf16* __restrict__ Q0l, long ldq0,
    int act1, const __bf16* __restrict__ A1h, const __bf16* __restrict__ A1l,
    long lda1_, int K01,
    const __bf16* __restrict__ Wi1h, const __bf16* __restrict__ Wi1l,
    const __bf16* __restrict__ Wr1h, const __bf16* __restrict__ Wr1l,
    const float* __restrict__ bs1,
    const __bf16* __restrict__ S1h, const __bf16* __restrict__ S1l,
    __bf16* __restrict__ O1h, __bf16* __restrict__ O1l,
    __bf16* __restrict__ Q1h, __bf16* __restrict__ Q1l, long ldq1)
{
    const int blk = blockIdx.x;
    const int layer = blk >> 8;
    const int tile = blk & 255;

    const __bf16 *Ah, *Al, *Wih, *Wil, *Wrh, *Wrl, *Sh, *Sl;
    __bf16 *Oh, *Ol, *Qh, *Ql;
    const float* bs;
    long lda, ldq;
    int K0;
    if (layer == 0) {
        if (!act0) return;
        Ah = A0h; Al = A0l; lda = lda0_; K0 = K00;
        Wih = Wi0h; Wil = Wi0l; Wrh = Wr0h; Wrl = Wr0l; bs = bs0;
        Sh = S0h; Sl = S0l; Oh = O0h; Ol = O0l; Qh = Q0h; Ql = Q0l; ldq = ldq0;
    } else {
        if (!act1) return;
        Ah = A1h; Al = A1l; lda = lda1_; K0 = K01;
        Wih = Wi1h; Wil = Wi1l; Wrh = Wr1h; Wrl = Wr1l; bs = bs1;
        Sh = S1h; Sl = S1l; Oh = O1h; Ol = O1l; Qh = Q1h; Ql = Q1l; ldq = ldq1;
    }

    const int jt = tile & 31;          // 32 col tiles of 32
    const int bt = tile >> 5;          // 8 row tiles of 16
    const int wave = threadIdx.x >> 6; // 0..3 : K-split
    const int lane = threadIdx.x & 63;
    const int ln = lane & 15;
    const int q  = lane >> 4;

    const int Ktot = K0 + H_;          // 1280 (layer0) or 2048 (layer1)
    const int Kq = Ktot >> 2;          // per-wave K slice (multiple of 32)
    const int kbeg = wave * Kq;
    const int kend = kbeg + Kq;

    const int arow = bt * 16 + ln;
    const int br0 = jt * 32 + ln;
    const int br1 = br0 + 16;

    f32x4 acc0[3] = {{0,0,0,0},{0,0,0,0},{0,0,0,0}};
    f32x4 acc1[3] = {{0,0,0,0},{0,0,0,0},{0,0,0,0}};

    // ---- segment 0: input contribution, rows of Wih (stride K0)
    {
        int sb = kbeg, se = kend < K0 ? kend : K0;
        if (se > sb) {
            const __bf16* ap_h = Ah + (long)arow * lda + sb + q * 8;
            const __bf16* ap_l = Al + (long)arow * lda + sb + q * 8;
            const __bf16* b0h = Wih + (long)br0 * K0 + sb + q * 8;
            const __bf16* b0l = Wil + (long)br0 * K0 + sb + q * 8;
            const __bf16* b1h = Wih + (long)br1 * K0 + sb + q * 8;
            const __bf16* b1l = Wil + (long)br1 * K0 + sb + q * 8;
            int n = (se - sb) >> 5;
            #pragma unroll 2
            for (int c = 0; c < n; ++c) {
                bf16x8 a_h = *(const bf16x8*)(ap_h + c * 32);
                bf16x8 a_l = *(const bf16x8*)(ap_l + c * 32);
                bf16x8 w0h = *(const bf16x8*)(b0h + c * 32);
                bf16x8 w0l = *(const bf16x8*)(b0l + c * 32);
                bf16x8 w1h = *(const bf16x8*)(b1h + c * 32);
                bf16x8 w1l = *(const bf16x8*)(b1l + c * 32);
                mfma3(acc0, a_h, a_l, w0h, w0l);
                mfma3(acc1, a_h, a_l, w1h, w1l);
            }
        }
    }
    // ---- segment 1: recurrent contribution, state S (stride H_), Wr (stride H_)
    {
        int sb = kbeg > K0 ? kbeg - K0 : 0;
        int se = kend - K0;
        if (se > sb) {
            const __bf16* ap_h = Sh + (long)arow * H_ + sb + q * 8;
            const __bf16* ap_l = Sl + (long)arow * H_ + sb + q * 8;
            const __bf16* b0h = Wrh + (long)br0 * H_ + sb + q * 8;
            const __bf16* b0l = Wrl + (long)br0 * H_ + sb + q * 8;
            const __bf16* b1h = Wrh + (long)br1 * H_ + sb + q * 8;
            const __bf16* b1l = Wrl + (long)br1 * H_ + sb + q * 8;
            int n = (se - sb) >> 5;
            #pragma unroll 2
            for (int c = 0; c < n; ++c) {
                bf16x8 a_h = *(const bf16x8*)(ap_h + c * 32);
                bf16x8 a_l = *(const bf16x8*)(ap_l + c * 32);
                bf16x8 w0h = *(const bf16x8*)(b0h + c * 32);
                bf16x8 w0l = *(const bf16x8*)(b0l + c * 32);
                bf16x8 w1h = *(const bf16x8*)(b1h + c * 32);
                bf16x8 w1l = *(const bf16x8*)(b1l + c * 32);
                mfma3(acc0, a_h, a_l, w0h, w0l);
                mfma3(acc1, a_h, a_l, w1h, w1l);
            }
        }
    }

    // ---- LDS reduction across the 4 K-split waves (pad 33 to avoid conflicts)
    __shared__ float red[4 * 16 * 33];
    {
        float* my = red + wave * 528;
        f32x4 s0 = acc0[0] + acc0[1] + acc0[2];
        f32x4 s1 = acc1[0] + acc1[1] + acc1[2];
        // C/D layout: col=lane&15, row=(lane>>4)*4+r  [m89/m91]
        #pragma unroll
        for (int r = 0; r < 4; ++r) {
            my[(q * 4 + r) * 33 + ln] = s0[r];
            my[(q * 4 + r) * 33 + 16 + ln] = s1[r];
        }
    }
    __syncthreads();

    // ---- epilogue: 512 outputs, 2 per thread
    #pragma unroll
    for (int e = 0; e < 2; ++e) {
        int idx = threadIdx.x + e * 256;
        int row = idx >> 5;
        int col = idx & 31;
        int off = row * 33 + col;
        float v = red[off] + red[528 + off] + red[1056 + off] + red[1584 + off];
        int b = bt * 16 + row;
        int j = jt * 32 + col;
        float h = tanhf(v + bs[j]);
        __bf16 hh = (__bf16)h;
        __bf16 hl = (__bf16)(h - (float)hh);
        Oh[(long)b * H_ + j] = hh;
        Ol[(long)b * H_ + j] = hl;
        if (Qh) { Qh[(long)b * ldq + j] = hh; Ql[(long)b * ldq + j] = hl; }
    }
}

// ---------------------------------------------------------------- final FC
__global__ __launch_bounds__(128) void fc_kernel(const __bf16* __restrict__ sh,
                                                 const __bf16* __restrict__ sl,
                                                 const float* __restrict__ wt,
                                                 const float* __restrict__ bfc,
                                                 float* __restrict__ out) {
    int b = blockIdx.x;    // 128
    int o = threadIdx.x;   // 128
    const __bf16* hh = sh + (long)b * H_;
    const __bf16* hl = sl + (long)b * H_;
    float acc = 0.f;
    #pragma unroll 4
    for (int k = 0; k < H_; ++k)
        acc += ((float)hh[k] + (float)hl[k]) * wt[k * O_ + o];
    out[b * O_ + o] = acc + bfc[o];
}

// ---------------------------------------------------------------- launch

extern "C" void kernel_launch(void* const* d_in, const int* in_sizes, int n_in,
                              void* d_out, int out_size, void* d_ws, size_t ws_size,
                              hipStream_t stream) {
    const float* X     = (const float*)d_in[0];
    const float* Wih0  = (const float*)d_in[1];
    const float* Whh0  = (const float*)d_in[2];
    const float* bih0  = (const float*)d_in[3];
    const float* bhh0  = (const float*)d_in[4];
    const float* Wih1  = (const float*)d_in[5];
    const float* Whh1  = (const float*)d_in[6];
    const float* bih1  = (const float*)d_in[7];
    const float* bhh1  = (const float*)d_in[8];
    const float* Wfc   = (const float*)d_in[9];
    const float* bfc   = (const float*)d_in[10];
    float* out = (float*)d_out;

    // ---- workspace carve (256B aligned chunks)
    char* p = (char*)d_ws;
    auto alloc = [&](size_t bytes) -> void* {
        void* r = (void*)p;
        p += (bytes + 255) & ~(size_t)255;
        return r;
    };
    const size_t nX  = (size_t)B_ * T_ * I_;
    const size_t nW0 = (size_t)H_ * I_;
    const size_t nW  = (size_t)H_ * H_;
    const size_t nH1 = (size_t)B_ * T_ * H_;
    const size_t nS  = (size_t)B_ * H_;
    __bf16* Xh   = (__bf16*)alloc(nX * 2);
    __bf16* Xl   = (__bf16*)alloc(nX * 2);
    __bf16* W0h  = (__bf16*)alloc(nW0 * 2);
    __bf16* W0l  = (__bf16*)alloc(nW0 * 2);
    __bf16* Wh0h = (__bf16*)alloc(nW * 2);
    __bf16* Wh0l = (__bf16*)alloc(nW * 2);
    __bf16* Wi1h = (__bf16*)alloc(nW * 2);
    __bf16* Wi1l = (__bf16*)alloc(nW * 2);
    __bf16* Wh1h = (__bf16*)alloc(nW * 2);
    __bf16* Wh1l = (__bf16*)alloc(nW * 2);
    __bf16* h1h  = (__bf16*)alloc(nH1 * 2);
    __bf16* h1l  = (__bf16*)alloc(nH1 * 2);
    __bf16* s0ah = (__bf16*)alloc(nS * 2);
    __bf16* s0al = (__bf16*)alloc(nS * 2);
    __bf16* s0bh = (__bf16*)alloc(nS * 2);
    __bf16* s0bl = (__bf16*)alloc(nS * 2);
    __bf16* s1ah = (__bf16*)alloc(nS * 2);
    __bf16* s1al = (__bf16*)alloc(nS * 2);
    __bf16* s1bh = (__bf16*)alloc(nS * 2);
    __bf16* s1bl = (__bf16*)alloc(nS * 2);
    float* wfct  = (float*)alloc((size_t)H_ * O_ * 4);
    float* bs0   = (float*)alloc((size_t)H_ * 4);
    float* bs1   = (float*)alloc((size_t)H_ * 4);
    (void)ws_size; (void)n_in; (void)in_sizes; (void)out_size;

    // ---- precompute: hi/lo splits, bias sums, W_fc transpose
    split_kernel<<<2048, 256, 0, stream>>>(X, Xh, Xl, (int)nX);
    split_kernel<<<512, 256, 0, stream>>>(Wih0, W0h, W0l, (int)nW0);
    split_kernel<<<1024, 256, 0, stream>>>(Whh0, Wh0h, Wh0l, (int)nW);
    split_kernel<<<1024, 256, 0, stream>>>(Wih1, Wi1h, Wi1l, (int)nW);
    split_kernel<<<1024, 256, 0, stream>>>(Whh1, Wh1h, Wh1l, (int)nW);
    bias_sum_kernel<<<4, 256, 0, stream>>>(bih0, bhh0, bs0, H_);
    bias_sum_kernel<<<4, 256, 0, stream>>>(bih1, bhh1, bs1, H_);
    transpose_fc<<<(O_ * H_ + 255) / 256, 256, 0, stream>>>(Wfc, wfct);

    hipMemsetAsync(s0ah, 0, nS * 2, stream);
    hipMemsetAsync(s0al, 0, nS * 2, stream);
    hipMemsetAsync(s1ah, 0, nS * 2, stream);
    hipMemsetAsync(s1al, 0, nS * 2, stream);

    // ---- wavefront pipeline: launch k runs layer0 step k and layer1 step k-1
    for (int t = 0; t <= T_; ++t) {
        int act0 = (t < T_) ? 1 : 0;
        int act1 = (t >= 1) ? 1 : 0;
        int t0 = act0 ? t : 0;
        int t1 = act1 ? t - 1 : 0;
        const __bf16 *s0ih, *s0il, *s1ih, *s1il;
        __bf16 *s0oh, *s0ol, *s1oh, *s1ol;
        if ((t0 & 1) == 0) { s0ih = s0ah; s0il = s0al; s0oh = s0bh; s0ol = s0bl; }
        else               { s0ih = s0bh; s0il = s0bl; s0oh = s0ah; s0ol = s0al; }
        if ((t1 & 1) == 0) { s1ih = s1ah; s1il = s1al; s1oh = s1bh; s1ol = s1bl; }
        else               { s1ih = s1bh; s1il = s1bl; s1oh = s1ah; s1ol = s1al; }
        fused_step<<<512, 256, 0, stream>>>(
            act0, Xh + (long)t0 * I_, Xl + (long)t0 * I_, (long)T_ * I_, I_,
            W0h, W0l, Wh0h, Wh0l, bs0,
            s0ih, s0il, s0oh, s0ol,
            h1h + (long)t0 * H_, h1l + (long)t0 * H_, (long)T_ * H_,
            act1, h1h + (long)t1 * H_, h1l + (long)t1 * H_, (long)T_ * H_, H_,
            Wi1h, Wi1l, Wh1h, Wh1l, bs1,
            s1ih, s1il, s1oh, s1ol,
            (__bf16*)nullptr, (__bf16*)nullptr, 0);
    }

    // final layer1 state: t1=255 (odd) wrote the A buffers
    fc_kernel<<<B_, O_, 0, stream>>>(s1ah, s1al, wfct, bfc, out);
}